// Round 1
// 114.124 us; speedup vs baseline: 1.0375x; 1.0375x over previous
//
#include <hip/hip_runtime.h>

// Problem: A=8, B=16, N=M=1024, K=64. u:(A,B,N,K) f32, v:(A,B,M,K) f32.
// out0 = u * (dot(u_row, v_sum) > 0), out1 = v * (dot(v_row, u_sum) > 0)
//
// Single kernel, no cross-block sync: block = (batch, half). Each block reads
// the WHOLE batch (512 KB) to compute full-batch column sums locally; its own
// half stays in registers and is masked+written directly.
//
// Round-4 change: XCD-aware pair swizzle. Dispatch assigns XCD = blockIdx % 8
// (round-robin). Previously the two blocks sharing a batch (2b, 2b+1) landed
// on DIFFERENT XCDs, so the duplicate half-batch read missed the (per-XCD,
// non-coherent) L2 and paid HBM-class cost: 134 MB read + 67 MB write serial
// ~= 32 us, matching the measured ~33 us. Remap so both halves of a batch run
// on the SAME XCD: all 256 blocks are co-resident (1/CU), the pair streams
// the batch concurrently, and the second reader hits L2 / merges in-flight
// misses. Expected: FETCH ~134 MB -> ~70-80 MB, kernel ~33 -> ~24 us.

#define NBATCH 128        // A*B
#define NROW   1024       // N == M
#define KDIM   64
#define ELEMS_PER_TENSOR (128ull * 1024ull * 64ull)  // 8388608

typedef float floatx4 __attribute__((ext_vector_type(4)));  // for nontemporal builtin

__global__ __launch_bounds__(1024)
void fused_local_kernel(const float* __restrict__ u,
                        const float* __restrict__ v,
                        float* __restrict__ out) {
    const int bid   = blockIdx.x;        // 0..255  (== CU count: 1 block/CU)
    // XCD-pair swizzle: hardware places block bid on XCD (bid & 7).
    // slot = bid>>3 is the per-XCD sequence number (0..31). Give each XCD 16
    // whole batches; consecutive slots are the two halves of one batch, so
    // both readers of a batch share the same L2. Bijective: (xcd, slot>>1)
    // covers 8*16 = 128 batches exactly.
    const int xcd   = bid & 7;
    const int slot  = bid >> 3;          // 0..31
    const int batch = xcd * 16 + (slot >> 1);  // 0..127
    const int half  = slot & 1;          // own rows: [half*512, half*512+512)
    const int tid   = threadIdx.x;       // 0..1023
    const int k4    = tid & 15;          // float4 column group
    const int rg    = tid >> 4;          // 0..63 row group
    const int wave  = tid >> 6;          // 0..15

    const float4* ub = (const float4*)(u + (size_t)batch * NROW * KDIM);
    const float4* vb = (const float4*)(v + (size_t)batch * NROW * KDIM);

    // ---- Phase A: read full batch; own half -> registers, all -> col sums --
    const int r_own0 = half * 512 + rg;
    const int r_oth0 = (1 - half) * 512 + rg;

    float4 ur[8], vr[8];
    float4 su = make_float4(0.f, 0.f, 0.f, 0.f);   // u colsum partial
    float4 sv = make_float4(0.f, 0.f, 0.f, 0.f);   // v colsum partial
    #pragma unroll
    for (int i = 0; i < 8; ++i) {
        size_t io = (size_t)(r_own0 + 64 * i) * 16 + k4;  // wave: 4 rows x 1KB, coalesced
        ur[i] = ub[io];
        vr[i] = vb[io];
        su.x += ur[i].x; su.y += ur[i].y; su.z += ur[i].z; su.w += ur[i].w;
        sv.x += vr[i].x; sv.y += vr[i].y; sv.z += vr[i].z; sv.w += vr[i].w;
    }
    #pragma unroll
    for (int i = 0; i < 8; ++i) {
        size_t ix = (size_t)(r_oth0 + 64 * i) * 16 + k4;
        float4 a = ub[ix];
        float4 b = vb[ix];
        su.x += a.x; su.y += a.y; su.z += a.z; su.w += a.w;
        sv.x += b.x; sv.y += b.y; sv.z += b.z; sv.w += b.w;
    }

    // ---- Reduce col sums: shfl across the 4 row-groups within each wave ----
    // lanes sharing k4 differ by 16/32 in lane id
    su.x += __shfl_xor(su.x, 16); su.y += __shfl_xor(su.y, 16);
    su.z += __shfl_xor(su.z, 16); su.w += __shfl_xor(su.w, 16);
    su.x += __shfl_xor(su.x, 32); su.y += __shfl_xor(su.y, 32);
    su.z += __shfl_xor(su.z, 32); su.w += __shfl_xor(su.w, 32);
    sv.x += __shfl_xor(sv.x, 16); sv.y += __shfl_xor(sv.y, 16);
    sv.z += __shfl_xor(sv.z, 16); sv.w += __shfl_xor(sv.w, 16);
    sv.x += __shfl_xor(sv.x, 32); sv.y += __shfl_xor(sv.y, 32);
    sv.z += __shfl_xor(sv.z, 32); sv.w += __shfl_xor(sv.w, 32);

    __shared__ float4 red_u[16][16];   // [wave][k4]
    __shared__ float4 red_v[16][16];
    __shared__ float4 fsum[2][16];     // [0]=v colsum (masks u), [1]=u colsum
    if ((tid & 63) < 16) {             // lane 0..15 holds k4 = lane
        red_u[wave][k4] = su;
        red_v[wave][k4] = sv;
    }
    __syncthreads();

    if (tid < 32) {
        const int which = tid >> 4;    // 0 -> v colsum, 1 -> u colsum
        const int c     = tid & 15;
        float4 t = make_float4(0.f, 0.f, 0.f, 0.f);
        if (which == 0) {
            #pragma unroll
            for (int i = 0; i < 16; ++i) {
                float4 b = red_v[i][c];
                t.x += b.x; t.y += b.y; t.z += b.z; t.w += b.w;
            }
        } else {
            #pragma unroll
            for (int i = 0; i < 16; ++i) {
                float4 a = red_u[i][c];
                t.x += a.x; t.y += a.y; t.z += a.z; t.w += a.w;
            }
        }
        fsum[which][c] = t;
    }
    __syncthreads();

    const float4 vs = fsum[0][k4];     // masks u rows
    const float4 us = fsum[1][k4];     // masks v rows

    // ---- Phase B: mask own half from registers, streaming stores ----------
    float* ou = out + (size_t)batch * NROW * KDIM;
    float* ov = out + ELEMS_PER_TENSOR + (size_t)batch * NROW * KDIM;

    #pragma unroll
    for (int i = 0; i < 8; ++i) {
        size_t io = (size_t)(r_own0 + 64 * i) * 16 + k4;

        float pu = ur[i].x * vs.x + ur[i].y * vs.y + ur[i].z * vs.z + ur[i].w * vs.w;
        pu += __shfl_xor(pu, 1);
        pu += __shfl_xor(pu, 2);
        pu += __shfl_xor(pu, 4);
        pu += __shfl_xor(pu, 8);
        float mu = (pu > 0.f) ? 1.f : 0.f;
        floatx4 outu = { ur[i].x * mu, ur[i].y * mu, ur[i].z * mu, ur[i].w * mu };
        __builtin_nontemporal_store(outu, (floatx4*)(ou + io * 4));

        float pv = vr[i].x * us.x + vr[i].y * us.y + vr[i].z * us.z + vr[i].w * us.w;
        pv += __shfl_xor(pv, 1);
        pv += __shfl_xor(pv, 2);
        pv += __shfl_xor(pv, 4);
        pv += __shfl_xor(pv, 8);
        float mv = (pv > 0.f) ? 1.f : 0.f;
        floatx4 outv = { vr[i].x * mv, vr[i].y * mv, vr[i].z * mv, vr[i].w * mv };
        __builtin_nontemporal_store(outv, (floatx4*)(ov + io * 4));
    }
}

extern "C" void kernel_launch(void* const* d_in, const int* in_sizes, int n_in,
                              void* d_out, int out_size, void* d_ws, size_t ws_size,
                              hipStream_t stream) {
    const float* u = (const float*)d_in[0];
    const float* v = (const float*)d_in[1];
    float* out = (float*)d_out;

    fused_local_kernel<<<dim3(256), dim3(1024), 0, stream>>>(u, v, out);
}